// Round 1
// baseline (272.116 us; speedup 1.0000x reference)
//
#include <hip/hip_runtime.h>

// ---------- types ----------
typedef __bf16 bf16x8 __attribute__((ext_vector_type(8)));
typedef float f32x4 __attribute__((ext_vector_type(4)));

__device__ __forceinline__ unsigned short f2bf(float f) {
    unsigned int u = __float_as_uint(f);
    unsigned int r = (u + 0x7FFFu + ((u >> 16) & 1u)) >> 16;
    return (unsigned short)r;
}

__device__ __forceinline__ bf16x8 load_frag(const unsigned short* p) {
    int4 v = *reinterpret_cast<const int4*>(p);
    return __builtin_bit_cast(bf16x8, v);
}

// ---------- small converters ----------
__global__ __launch_bounds__(256) void f32_to_bf16(const float* __restrict__ in,
                                                   unsigned short* __restrict__ out, int n) {
    int i = blockIdx.x * 256 + threadIdx.x;
    if (i < n) out[i] = f2bf(in[i]);
}

__global__ __launch_bounds__(256) void concat_w(const float* __restrict__ wq,
                                                const float* __restrict__ wk,
                                                const float* __restrict__ wv,
                                                unsigned short* __restrict__ out) {
    int i = blockIdx.x * 256 + threadIdx.x;      // 0 .. 3*1024*1024-1
    int r = i >> 20;
    const float* src = (r == 0) ? wq : ((r == 1) ? wk : wv);
    out[i] = f2bf(src[i & 1048575]);
}

__global__ __launch_bounds__(256) void rope_table(float* __restrict__ cost,
                                                  float* __restrict__ sint) {
    int i = blockIdx.x * 256 + threadIdx.x;      // 2048*32
    int t = i >> 5, d = i & 31;
    float inv = powf(10000.0f, -(float)d / 32.0f);
    float f = (float)t * inv;
    cost[i] = cosf(f);
    sint[i] = sinf(f);
}

// ---------- GEMM: C[M,N] = A[M,K] @ B[N,K]^T  (bf16 in, fp32 out) ----------
#define GBM 128
#define GBN 128
#define GBK 64
#define GPAD 8

__global__ __launch_bounds__(256) void gemm_bf16(const unsigned short* __restrict__ A,
                                                 const unsigned short* __restrict__ B,
                                                 float* __restrict__ C,
                                                 int N, int K) {
    __shared__ __align__(16) unsigned short As[GBM][GBK + GPAD];
    __shared__ __align__(16) unsigned short Bs[GBN][GBK + GPAD];
    int tid = threadIdx.x;
    int lane = tid & 63;
    int wid = tid >> 6;
    int wm = wid >> 1, wn = wid & 1;
    int m0 = blockIdx.x * GBM;
    int n0 = blockIdx.y * GBN;

    f32x4 acc[4][4] = {};

    int lrow = tid >> 3;         // 0..31
    int lcol = (tid & 7) * 8;    // 0..56

    for (int k0 = 0; k0 < K; k0 += GBK) {
        __syncthreads();
        for (int rr = 0; rr < 4; ++rr) {
            int row = rr * 32 + lrow;
            *reinterpret_cast<int4*>(&As[row][lcol]) =
                *reinterpret_cast<const int4*>(&A[(size_t)(m0 + row) * K + k0 + lcol]);
            *reinterpret_cast<int4*>(&Bs[row][lcol]) =
                *reinterpret_cast<const int4*>(&B[(size_t)(n0 + row) * K + k0 + lcol]);
        }
        __syncthreads();
        for (int kk = 0; kk < 2; ++kk) {
            int krd = kk * 32 + (lane >> 4) * 8;
            bf16x8 af[4], bfr[4];
            for (int i = 0; i < 4; ++i) af[i]  = load_frag(&As[wm * 64 + i * 16 + (lane & 15)][krd]);
            for (int j = 0; j < 4; ++j) bfr[j] = load_frag(&Bs[wn * 64 + j * 16 + (lane & 15)][krd]);
            for (int i = 0; i < 4; ++i)
                for (int j = 0; j < 4; ++j)
                    acc[i][j] = __builtin_amdgcn_mfma_f32_16x16x32_bf16(af[i], bfr[j], acc[i][j], 0, 0, 0);
        }
    }
    int r0 = (lane >> 4) * 4;
    int cc = lane & 15;
    for (int i = 0; i < 4; ++i)
        for (int j = 0; j < 4; ++j)
            for (int r = 0; r < 4; ++r) {
                int m = m0 + wm * 64 + i * 16 + r0 + r;
                int n = n0 + wn * 64 + j * 16 + cc;
                C[(size_t)m * N + n] = acc[i][j][r];
            }
}

// ---------- post: v-lerp + rmsnorm + rope + scale + layout [B,H,T,64] bf16 ----------
__global__ __launch_bounds__(256) void postprocess(const float* __restrict__ qkv,   // [4096][3072]
                                                   const float* __restrict__ v1,    // [B,T,H,64]
                                                   const float* __restrict__ lamb_p,
                                                   const float* __restrict__ cost,
                                                   const float* __restrict__ sint,
                                                   unsigned short* __restrict__ qb,
                                                   unsigned short* __restrict__ kb,
                                                   unsigned short* __restrict__ vb) {
    int gid = blockIdx.x * 4 + (threadIdx.x >> 6);   // (b,t,h) row id, 0..65535
    int lane = threadIdx.x & 63;
    int h = gid & 15;
    int t = (gid >> 4) & 2047;
    int b = gid >> 15;
    int m = b * 2048 + t;
    float lamb = lamb_p[0];

    float q = qkv[(size_t)m * 3072 + h * 64 + lane];
    float k = qkv[(size_t)m * 3072 + 1024 + h * 64 + lane];
    float v = qkv[(size_t)m * 3072 + 2048 + h * 64 + lane];
    float v1v = v1[((size_t)m * 16 + h) * 64 + lane];
    float vf = (1.0f - lamb) * v + lamb * v1v;

    float sq = q * q, sk = k * k;
    for (int msk = 1; msk < 64; msk <<= 1) {
        sq += __shfl_xor(sq, msk, 64);
        sk += __shfl_xor(sk, msk, 64);
    }
    q *= rsqrtf(sq * (1.0f / 64.0f) + 1e-6f);
    k *= rsqrtf(sk * (1.0f / 64.0f) + 1e-6f);

    int d = lane & 31;
    float c = cost[t * 32 + d], s = sint[t * 32 + d];
    float qp = __shfl_xor(q, 32, 64);
    float kp = __shfl_xor(k, 32, 64);
    float qo = (lane < 32) ? (q * c + qp * s) : (q * c - qp * s);
    float ko = (lane < 32) ? (k * c + kp * s) : (k * c - kp * s);
    qo *= 0.125f;   // fold softmax scale (1/sqrt(64)) into q

    size_t oidx = ((size_t)((b * 16 + h) * 2048 + t)) * 64 + lane;
    qb[oidx] = f2bf(qo);
    kb[oidx] = f2bf(ko);
    vb[oidx] = f2bf(vf);
}

// ---------- flash attention, causal, bf16 MFMA ----------
__global__ __launch_bounds__(256) void attn(const unsigned short* __restrict__ qb,
                                            const unsigned short* __restrict__ kb,
                                            const unsigned short* __restrict__ vb,
                                            unsigned short* __restrict__ yb) {   // [B,T,1024]
    __shared__ __align__(16) unsigned short Ks[64][72];
    __shared__ __align__(16) unsigned short Vt[64][72];         // [d][kv]
    __shared__ __align__(16) unsigned short Plds[4][16][72];
    int tid = threadIdx.x;
    int lane = tid & 63;
    int w = tid >> 6;
    int qt = blockIdx.x;
    int bh = blockIdx.y;            // b*16 + h
    int b = bh >> 4, h = bh & 15;
    int q0 = qt * 64;
    const size_t base = (size_t)bh * 2048 * 64;

    bf16x8 qf[2];
    {
        int qrow = q0 + w * 16 + (lane & 15);
        for (int kk = 0; kk < 2; ++kk)
            qf[kk] = load_frag(&qb[base + (size_t)qrow * 64 + kk * 32 + (lane >> 4) * 8]);
    }

    f32x4 oacc[4] = {};
    float mrun[4], lrun[4];
    for (int r = 0; r < 4; ++r) { mrun[r] = -1e30f; lrun[r] = 0.0f; }

    int lr = tid >> 3;          // 0..31
    int lc = (tid & 7) * 8;     // 0..56

    for (int kt = 0; kt <= qt; ++kt) {
        __syncthreads();
        for (int rr = 0; rr < 2; ++rr) {
            int row = rr * 32 + lr;
            *reinterpret_cast<int4*>(&Ks[row][lc]) =
                *reinterpret_cast<const int4*>(&kb[base + (size_t)(kt * 64 + row) * 64 + lc]);
            int4 vv = *reinterpret_cast<const int4*>(&vb[base + (size_t)(kt * 64 + row) * 64 + lc]);
            unsigned short* vs = reinterpret_cast<unsigned short*>(&vv);
            for (int j = 0; j < 8; ++j) Vt[lc + j][row] = vs[j];
        }
        __syncthreads();

        f32x4 sacc[4] = {};
        for (int kk = 0; kk < 2; ++kk) {
            int krd = kk * 32 + (lane >> 4) * 8;
            for (int nt = 0; nt < 4; ++nt) {
                bf16x8 kf = load_frag(&Ks[nt * 16 + (lane & 15)][krd]);
                sacc[nt] = __builtin_amdgcn_mfma_f32_16x16x32_bf16(qf[kk], kf, sacc[nt], 0, 0, 0);
            }
        }

        if (kt == qt) {
            for (int nt = 0; nt < 4; ++nt)
                for (int r = 0; r < 4; ++r) {
                    int kidx = kt * 64 + nt * 16 + (lane & 15);
                    int qidx = q0 + w * 16 + (lane >> 4) * 4 + r;
                    if (kidx > qidx) sacc[nt][r] = -1e30f;
                }
        }

        float alpha[4];
        for (int r = 0; r < 4; ++r) {
            float mx = fmaxf(fmaxf(sacc[0][r], sacc[1][r]), fmaxf(sacc[2][r], sacc[3][r]));
            for (int msk = 1; msk < 16; msk <<= 1) mx = fmaxf(mx, __shfl_xor(mx, msk, 64));
            float mnew = fmaxf(mrun[r], mx);
            alpha[r] = __expf(mrun[r] - mnew);
            mrun[r] = mnew;
            float rs = 0.0f;
            for (int nt = 0; nt < 4; ++nt) {
                float p = __expf(sacc[nt][r] - mnew);
                sacc[nt][r] = p;
                rs += p;
            }
            for (int msk = 1; msk < 16; msk <<= 1) rs += __shfl_xor(rs, msk, 64);
            lrun[r] = lrun[r] * alpha[r] + rs;
        }

        for (int nt = 0; nt < 4; ++nt)
            for (int r = 0; r < 4; ++r)
                Plds[w][(lane >> 4) * 4 + r][nt * 16 + (lane & 15)] = f2bf(sacc[nt][r]);

        for (int nt = 0; nt < 4; ++nt)
            for (int r = 0; r < 4; ++r)
                oacc[nt][r] *= alpha[r];

        __syncthreads();   // order P writes vs int4 re-reads (TBAA safety)

        for (int kk = 0; kk < 2; ++kk) {
            int krd = kk * 32 + (lane >> 4) * 8;
            bf16x8 pf = load_frag(&Plds[w][lane & 15][krd]);
            for (int nt = 0; nt < 4; ++nt) {
                bf16x8 vf = load_frag(&Vt[nt * 16 + (lane & 15)][krd]);
                oacc[nt] = __builtin_amdgcn_mfma_f32_16x16x32_bf16(pf, vf, oacc[nt], 0, 0, 0);
            }
        }
    }

    for (int nt = 0; nt < 4; ++nt)
        for (int r = 0; r < 4; ++r) {
            int q = q0 + w * 16 + (lane >> 4) * 4 + r;
            float o = oacc[nt][r] / lrun[r];
            yb[((size_t)(b * 2048 + q) * 16 + h) * 64 + nt * 16 + (lane & 15)] = f2bf(o);
        }
}

// ---------- launch ----------
extern "C" void kernel_launch(void* const* d_in, const int* in_sizes, int n_in,
                              void* d_out, int out_size, void* d_ws, size_t ws_size,
                              hipStream_t stream) {
    const float* x      = (const float*)d_in[0];   // [2,2048,1024]
    const float* v1     = (const float*)d_in[1];   // [2,2048,16,64]
    const float* w_q    = (const float*)d_in[2];
    const float* w_k    = (const float*)d_in[3];
    const float* w_v    = (const float*)d_in[4];
    const float* w_proj = (const float*)d_in[5];
    const float* lamb   = (const float*)d_in[6];
    float* out = (float*)d_out;

    char* ws = (char*)d_ws;
    unsigned short* xb     = (unsigned short*)(ws + 0);
    unsigned short* wqkv_b = (unsigned short*)(ws + (8u  << 20));
    unsigned short* wproj_b= (unsigned short*)(ws + (14u << 20));
    float*          qkv    = (float*)        (ws + (16u << 20));   // [4096][3072]
    unsigned short* qb     = (unsigned short*)(ws + (64u << 20));  // [B,H,T,64]
    unsigned short* kb     = (unsigned short*)(ws + (72u << 20));
    unsigned short* vb     = (unsigned short*)(ws + (80u << 20));
    unsigned short* yb     = (unsigned short*)(ws + (88u << 20));  // [B,T,1024]
    float*          cost   = (float*)        (ws + (96u << 20));
    float*          sint   = (float*)        (ws + (96u << 20) + 262144);

    f32_to_bf16<<<16384, 256, 0, stream>>>(x, xb, 4096 * 1024);
    concat_w<<<12288, 256, 0, stream>>>(w_q, w_k, w_v, wqkv_b);
    f32_to_bf16<<<4096, 256, 0, stream>>>(w_proj, wproj_b, 1024 * 1024);
    rope_table<<<256, 256, 0, stream>>>(cost, sint);

    gemm_bf16<<<dim3(32, 24), 256, 0, stream>>>(xb, wqkv_b, qkv, 3072, 1024);

    postprocess<<<16384, 256, 0, stream>>>(qkv, v1, lamb, cost, sint, qb, kb, vb);

    attn<<<dim3(32, 32), 256, 0, stream>>>(qb, kb, vb, yb);

    gemm_bf16<<<dim3(32, 8), 256, 0, stream>>>(yb, wproj_b, out, 1024, 1024);

    hipMemcpyAsync(out + 4194304, v1, 4194304 * sizeof(float),
                   hipMemcpyDeviceToDevice, stream);
}

// Round 2
// 170.189 us; speedup vs baseline: 1.5989x; 1.5989x over previous
//
#include <hip/hip_runtime.h>

// ---------- types ----------
typedef __bf16 bf16x8 __attribute__((ext_vector_type(8)));
typedef float f32x4 __attribute__((ext_vector_type(4)));
typedef float f32x16 __attribute__((ext_vector_type(16)));

__device__ __forceinline__ unsigned short f2bf(float f) {
    unsigned int u = __float_as_uint(f);
    unsigned int r = (u + 0x7FFFu + ((u >> 16) & 1u)) >> 16;
    return (unsigned short)r;
}

__device__ __forceinline__ unsigned int packbf2(float a, float b) {
    return (unsigned int)f2bf(a) | ((unsigned int)f2bf(b) << 16);
}

__device__ __forceinline__ bf16x8 load_frag(const unsigned short* p) {
    int4 v = *reinterpret_cast<const int4*>(p);
    return __builtin_bit_cast(bf16x8, v);
}

// ---------- small converters ----------
__global__ __launch_bounds__(256) void f32_to_bf16(const float* __restrict__ in,
                                                   unsigned short* __restrict__ out, int n) {
    int i = blockIdx.x * 256 + threadIdx.x;
    if (i < n) out[i] = f2bf(in[i]);
}

__global__ __launch_bounds__(256) void concat_w(const float* __restrict__ wq,
                                                const float* __restrict__ wk,
                                                const float* __restrict__ wv,
                                                unsigned short* __restrict__ out) {
    int i = blockIdx.x * 256 + threadIdx.x;      // 0 .. 3*1024*1024-1
    int r = i >> 20;
    const float* src = (r == 0) ? wq : ((r == 1) ? wk : wv);
    out[i] = f2bf(src[i & 1048575]);
}

__global__ __launch_bounds__(256) void rope_table(float* __restrict__ cost,
                                                  float* __restrict__ sint) {
    int i = blockIdx.x * 256 + threadIdx.x;      // 2048*32
    int t = i >> 5, d = i & 31;
    float inv = powf(10000.0f, -(float)d / 32.0f);
    float f = (float)t * inv;
    cost[i] = cosf(f);
    sint[i] = sinf(f);
}

// ---------- GEMM: C[M,N] = A[M,K] @ B[N,K]^T  (bf16 in, fp32 out) ----------
#define GBM 128
#define GBN 128
#define GBK 64
#define GPAD 8

__global__ __launch_bounds__(256) void gemm_bf16(const unsigned short* __restrict__ A,
                                                 const unsigned short* __restrict__ B,
                                                 float* __restrict__ C,
                                                 int N, int K) {
    __shared__ __align__(16) unsigned short As[GBM][GBK + GPAD];
    __shared__ __align__(16) unsigned short Bs[GBN][GBK + GPAD];
    int tid = threadIdx.x;
    int lane = tid & 63;
    int wid = tid >> 6;
    int wm = wid >> 1, wn = wid & 1;
    int m0 = blockIdx.x * GBM;
    int n0 = blockIdx.y * GBN;

    f32x4 acc[4][4] = {};

    int lrow = tid >> 3;         // 0..31
    int lcol = (tid & 7) * 8;    // 0..56

    for (int k0 = 0; k0 < K; k0 += GBK) {
        __syncthreads();
        for (int rr = 0; rr < 4; ++rr) {
            int row = rr * 32 + lrow;
            *reinterpret_cast<int4*>(&As[row][lcol]) =
                *reinterpret_cast<const int4*>(&A[(size_t)(m0 + row) * K + k0 + lcol]);
            *reinterpret_cast<int4*>(&Bs[row][lcol]) =
                *reinterpret_cast<const int4*>(&B[(size_t)(n0 + row) * K + k0 + lcol]);
        }
        __syncthreads();
        for (int kk = 0; kk < 2; ++kk) {
            int krd = kk * 32 + (lane >> 4) * 8;
            bf16x8 af[4], bfr[4];
            for (int i = 0; i < 4; ++i) af[i]  = load_frag(&As[wm * 64 + i * 16 + (lane & 15)][krd]);
            for (int j = 0; j < 4; ++j) bfr[j] = load_frag(&Bs[wn * 64 + j * 16 + (lane & 15)][krd]);
            for (int i = 0; i < 4; ++i)
                for (int j = 0; j < 4; ++j)
                    acc[i][j] = __builtin_amdgcn_mfma_f32_16x16x32_bf16(af[i], bfr[j], acc[i][j], 0, 0, 0);
        }
    }
    int r0 = (lane >> 4) * 4;
    int cc = lane & 15;
    for (int i = 0; i < 4; ++i)
        for (int j = 0; j < 4; ++j)
            for (int r = 0; r < 4; ++r) {
                int m = m0 + wm * 64 + i * 16 + r0 + r;
                int n = n0 + wn * 64 + j * 16 + cc;
                C[(size_t)m * N + n] = acc[i][j][r];
            }
}

// ---------- post: v-lerp + rmsnorm + rope + scale + layout [B,H,T,64] bf16 ----------
__global__ __launch_bounds__(256) void postprocess(const float* __restrict__ qkv,   // [4096][3072]
                                                   const float* __restrict__ v1,    // [B,T,H,64]
                                                   const float* __restrict__ lamb_p,
                                                   const float* __restrict__ cost,
                                                   const float* __restrict__ sint,
                                                   unsigned short* __restrict__ qb,
                                                   unsigned short* __restrict__ kb,
                                                   unsigned short* __restrict__ vb) {
    int gid = blockIdx.x * 4 + (threadIdx.x >> 6);   // (b,t,h) row id, 0..65535
    int lane = threadIdx.x & 63;
    int h = gid & 15;
    int t = (gid >> 4) & 2047;
    int b = gid >> 15;
    int m = b * 2048 + t;
    float lamb = lamb_p[0];

    float q = qkv[(size_t)m * 3072 + h * 64 + lane];
    float k = qkv[(size_t)m * 3072 + 1024 + h * 64 + lane];
    float v = qkv[(size_t)m * 3072 + 2048 + h * 64 + lane];
    float v1v = v1[((size_t)m * 16 + h) * 64 + lane];
    float vf = (1.0f - lamb) * v + lamb * v1v;

    float sq = q * q, sk = k * k;
    for (int msk = 1; msk < 64; msk <<= 1) {
        sq += __shfl_xor(sq, msk, 64);
        sk += __shfl_xor(sk, msk, 64);
    }
    q *= rsqrtf(sq * (1.0f / 64.0f) + 1e-6f);
    k *= rsqrtf(sk * (1.0f / 64.0f) + 1e-6f);

    int d = lane & 31;
    float c = cost[t * 32 + d], s = sint[t * 32 + d];
    float qp = __shfl_xor(q, 32, 64);
    float kp = __shfl_xor(k, 32, 64);
    float qo = (lane < 32) ? (q * c + qp * s) : (q * c - qp * s);
    float ko = (lane < 32) ? (k * c + kp * s) : (k * c - kp * s);
    qo *= 0.125f;   // fold softmax scale (1/sqrt(64)) into q

    size_t oidx = ((size_t)((b * 16 + h) * 2048 + t)) * 64 + lane;
    qb[oidx] = f2bf(qo);
    kb[oidx] = f2bf(ko);
    vb[oidx] = f2bf(vf);
}

// ---------- V transpose: vb [bh][t][64] -> vt [bh][64][t] ----------
__global__ __launch_bounds__(256) void transpose_v(const unsigned short* __restrict__ vb,
                                                   unsigned short* __restrict__ vt) {
    __shared__ __align__(16) unsigned short tile[64][72];
    int bh = blockIdx.y;
    int t0 = blockIdx.x * 64;
    int tid = threadIdx.x;
    int r = tid >> 3;            // 0..31
    int c = (tid & 7) * 8;       // 0..56
    const unsigned short* src = vb + ((size_t)bh * 2048 + t0) * 64;
    *reinterpret_cast<int4*>(&tile[r][c]) =
        *reinterpret_cast<const int4*>(&src[(size_t)r * 64 + c]);
    *reinterpret_cast<int4*>(&tile[r + 32][c]) =
        *reinterpret_cast<const int4*>(&src[(size_t)(r + 32) * 64 + c]);
    __syncthreads();
    unsigned short* dst = vt + (size_t)bh * 64 * 2048 + t0;
    unsigned short tmp[8];
#pragma unroll
    for (int j = 0; j < 8; ++j) tmp[j] = tile[c + j][r];
    *reinterpret_cast<int4*>(&dst[(size_t)r * 2048 + c]) = *reinterpret_cast<int4*>(tmp);
#pragma unroll
    for (int j = 0; j < 8; ++j) tmp[j] = tile[c + j][r + 32];
    *reinterpret_cast<int4*>(&dst[(size_t)(r + 32) * 2048 + c]) = *reinterpret_cast<int4*>(tmp);
}

// ---------- flash attention, causal, swapped-QK^T 32x32 MFMA ----------
// Block: 256 thr (4 waves), each wave owns 32 q rows -> 128 q rows/block.
// Grid: 512 = 16 qtiles x 32 bh, paired heavy/light for balance.
__global__ __launch_bounds__(256) void attn(const unsigned short* __restrict__ qb,
                                            const unsigned short* __restrict__ kb,
                                            const unsigned short* __restrict__ vt,  // [bh][64][2048]
                                            unsigned short* __restrict__ yb) {      // [B,T,1024]
    __shared__ __align__(16) unsigned short Ks[64][72];   // [kv][d]
    __shared__ __align__(16) unsigned short Vt[64][72];   // [d][kv]
    int tid = threadIdx.x;
    int lane = tid & 63;
    int w = tid >> 6;
    int hi = lane >> 5;          // 0/1
    int l31 = lane & 31;

    int bid = blockIdx.x;
    int i = bid >> 5;
    int bh = bid & 31;
    int qt = (i < 8) ? (15 - i) : (i - 8);   // heavy blocks first; bid & bid+256 pair to const work
    int q0 = qt * 128;
    int b = bh >> 4, h = bh & 15;
    const size_t base = (size_t)bh * 2048 * 64;
    const unsigned short* vtb = vt + (size_t)bh * 64 * 2048;
    int ktmax = 2 * qt + 1;

    // Q fragments (B-operand): col q = l31, k = hi*8+j within each 16-d slice
    bf16x8 qf[4];
    int qrow = q0 + w * 32 + l31;
#pragma unroll
    for (int kd = 0; kd < 4; ++kd)
        qf[kd] = load_frag(&qb[base + (size_t)qrow * 64 + kd * 16 + hi * 8]);

    f32x16 oacc[2] = {};
    float lrun = 0.0f;

    // staging assignment
    int srow = tid >> 3;            // 0..31
    int scol = (tid & 7) * 8;       // 0..56
    int4 kr0, kr1, vr0, vr1;
#define LOADT(kt_)                                                                          \
    do {                                                                                    \
        kr0 = *reinterpret_cast<const int4*>(&kb[base + (size_t)((kt_)*64 + srow) * 64 + scol]);      \
        kr1 = *reinterpret_cast<const int4*>(&kb[base + (size_t)((kt_)*64 + srow + 32) * 64 + scol]); \
        vr0 = *reinterpret_cast<const int4*>(&vtb[(size_t)srow * 2048 + (kt_)*64 + scol]);            \
        vr1 = *reinterpret_cast<const int4*>(&vtb[(size_t)(srow + 32) * 2048 + (kt_)*64 + scol]);     \
    } while (0)

    LOADT(0);
    int qwlo = q0 + w * 32;
    int qwhi = qwlo + 31;

    for (int kt = 0; kt <= ktmax; ++kt) {
        __syncthreads();
        *reinterpret_cast<int4*>(&Ks[srow][scol]) = kr0;
        *reinterpret_cast<int4*>(&Ks[srow + 32][scol]) = kr1;
        *reinterpret_cast<int4*>(&Vt[srow][scol]) = vr0;
        *reinterpret_cast<int4*>(&Vt[srow + 32][scol]) = vr1;
        __syncthreads();
        if (kt < ktmax) LOADT(kt + 1);

        if (kt * 64 <= qwhi) {
            // S^T tiles: m = kv (32 per tile), n = q
            f32x16 sacc[2] = {};
#pragma unroll
            for (int nt = 0; nt < 2; ++nt)
#pragma unroll
                for (int kd = 0; kd < 4; ++kd) {
                    bf16x8 kf = load_frag(&Ks[nt * 32 + l31][kd * 16 + hi * 8]);
                    sacc[nt] = __builtin_amdgcn_mfma_f32_32x32x16_bf16(kf, qf[kd], sacc[nt], 0, 0, 0);
                }

            // softmax with fixed max=0 (|s| <= 8 guaranteed: unit-RMS rows, scale 1/8)
            bool diag = (kt * 64 + 63 > qwlo);
            float rs = 0.0f;
#pragma unroll
            for (int nt = 0; nt < 2; ++nt)
#pragma unroll
                for (int r = 0; r < 16; ++r) {
                    float s = sacc[nt][r];
                    if (diag) {
                        int kvg = kt * 64 + nt * 32 + (r & 3) + 8 * (r >> 2) + 4 * hi;
                        if (kvg > qrow) s = -3.0e38f;
                    }
                    float e = __expf(s);
                    sacc[nt][r] = e;
                    rs += e;
                }
            rs += __shfl_xor(rs, 32, 64);
            lrun += rs;

            // pack P to bf16 pairs: wA = kv {+0,+1}, wB = kv {+2,+3} of each 4-group
            unsigned int wA[2][4], wB[2][4];
#pragma unroll
            for (int nt = 0; nt < 2; ++nt)
#pragma unroll
                for (int rr = 0; rr < 4; ++rr) {
                    wA[nt][rr] = packbf2(sacc[nt][4 * rr + 0], sacc[nt][4 * rr + 1]);
                    wB[nt][rr] = packbf2(sacc[nt][4 * rr + 2], sacc[nt][4 * rr + 3]);
                }

            // PV: 4 k-slices of 16 kv; A-frag assembled via half-swap shuffles
#pragma unroll
            for (int ks = 0; ks < 4; ++ks) {
                int nt = ks >> 1;
                int b2 = (ks & 1) * 2;
                unsigned int x0 = wA[nt][b2], y0 = wA[nt][b2 + 1];
                unsigned int x1 = wB[nt][b2], y1 = wB[nt][b2 + 1];
                unsigned int x0s = __shfl_xor(x0, 32, 64);
                unsigned int y0s = __shfl_xor(y0, 32, 64);
                unsigned int x1s = __shfl_xor(x1, 32, 64);
                unsigned int y1s = __shfl_xor(y1, 32, 64);
                uint4 pa;
                pa.x = (hi == 0) ? x0 : y0s;   // kv 16ks+8hi+{0,1}
                pa.y = (hi == 0) ? x1 : y1s;   // +{2,3}
                pa.z = (hi == 0) ? x0s : y0;   // +{4,5}
                pa.w = (hi == 0) ? x1s : y1;   // +{6,7}
                bf16x8 paf = __builtin_bit_cast(bf16x8, pa);
#pragma unroll
                for (int dt = 0; dt < 2; ++dt) {
                    bf16x8 vtf = load_frag(&Vt[dt * 32 + l31][ks * 16 + hi * 8]);
                    oacc[dt] = __builtin_amdgcn_mfma_f32_32x32x16_bf16(paf, vtf, oacc[dt], 0, 0, 0);
                }
            }
        }
    }

    float linv = 1.0f / lrun;
#pragma unroll
    for (int r = 0; r < 16; ++r) {
        int ql = (r & 3) + 8 * (r >> 2) + 4 * hi;
        float rv = __shfl(linv, ql, 64);
        int q = q0 + w * 32 + ql;
        size_t ro = ((size_t)(b * 2048 + q) * 16 + h) * 64;
        yb[ro + l31]      = f2bf(oacc[0][r] * rv);
        yb[ro + 32 + l31] = f2bf(oacc[1][r] * rv);
    }
#undef LOADT
}

// ---------- launch ----------
extern "C" void kernel_launch(void* const* d_in, const int* in_sizes, int n_in,
                              void* d_out, int out_size, void* d_ws, size_t ws_size,
                              hipStream_t stream) {
    const float* x      = (const float*)d_in[0];   // [2,2048,1024]
    const float* v1     = (const float*)d_in[1];   // [2,2048,16,64]
    const float* w_q    = (const float*)d_in[2];
    const float* w_k    = (const float*)d_in[3];
    const float* w_v    = (const float*)d_in[4];
    const float* w_proj = (const float*)d_in[5];
    const float* lamb   = (const float*)d_in[6];
    float* out = (float*)d_out;

    char* ws = (char*)d_ws;
    unsigned short* xb     = (unsigned short*)(ws + 0);
    unsigned short* wqkv_b = (unsigned short*)(ws + (8u  << 20));
    unsigned short* wproj_b= (unsigned short*)(ws + (14u << 20));
    float*          qkv    = (float*)        (ws + (16u << 20));   // [4096][3072] (dead after postprocess)
    unsigned short* vtp    = (unsigned short*)(ws + (16u << 20));  // [32][64][2048] reuses dead qkv
    unsigned short* qbuf   = (unsigned short*)(ws + (64u << 20));  // [B,H,T,64]
    unsigned short* kbuf   = (unsigned short*)(ws + (72u << 20));
    unsigned short* vbuf   = (unsigned short*)(ws + (80u << 20));
    unsigned short* ybuf   = (unsigned short*)(ws + (88u << 20));  // [B,T,1024]
    float*          cost   = (float*)        (ws + (96u << 20));
    float*          sint   = (float*)        (ws + (96u << 20) + 262144);

    f32_to_bf16<<<16384, 256, 0, stream>>>(x, xb, 4096 * 1024);
    concat_w<<<12288, 256, 0, stream>>>(w_q, w_k, w_v, wqkv_b);
    f32_to_bf16<<<4096, 256, 0, stream>>>(w_proj, wproj_b, 1024 * 1024);
    rope_table<<<256, 256, 0, stream>>>(cost, sint);

    gemm_bf16<<<dim3(32, 24), 256, 0, stream>>>(xb, wqkv_b, qkv, 3072, 1024);

    postprocess<<<16384, 256, 0, stream>>>(qkv, v1, lamb, cost, sint, qbuf, kbuf, vbuf);

    transpose_v<<<dim3(32, 32), 256, 0, stream>>>(vbuf, vtp);   // qkv is dead now

    attn<<<512, 256, 0, stream>>>(qbuf, kbuf, vtp, ybuf);

    gemm_bf16<<<dim3(32, 8), 256, 0, stream>>>(ybuf, wproj_b, out, 1024, 1024);

    hipMemcpyAsync(out + 4194304, v1, 4194304 * sizeof(float),
                   hipMemcpyDeviceToDevice, stream);
}